// Round 9
// baseline (248.463 us; speedup 1.0000x reference)
//
#include <hip/hip_runtime.h>
#include <math.h>

// B=4, S=4096, D=2048, E=64, K=2
#define NTOK    16384
#define DDIM    2048
#define NEXP    64
#define PSTRIDE (NTOK * NEXP)
#define ITERS   32                 // 32-k steps per wave (wave covers 1024 k)

typedef _Float16 half8   __attribute__((ext_vector_type(8)));
typedef float    floatx4 __attribute__((ext_vector_type(4)));

// ---------------------------------------------------------------------------
// W (fp32 [64][2048]) -> d_ws permuted so every wave B-fragment load is one
// fully-coalesced dwordx4: 16B chunk index g = ((((h*32+i)*4+j)*2+pl)*64+lane,
// holding hi (pl=0) or lo*2^11 (pl=1) of W[e=j*16+(lane&15)]
// [k = h*1024 + i*32 + (lane>>4)*8 .. +8).
// ---------------------------------------------------------------------------
__global__ __launch_bounds__(256) void wconv_kernel(
    const float* __restrict__ W, _Float16* __restrict__ ws)
{
    const int g    = blockIdx.x * 256 + threadIdx.x;   // 32768 chunks
    const int lane = g & 63;
    const int pl   = (g >> 6) & 1;
    const int j    = (g >> 7) & 3;
    const int i    = (g >> 9) & 31;
    const int h    = (g >> 14) & 1;
    const int e    = j * 16 + (lane & 15);
    const int k    = h * 1024 + i * 32 + (lane >> 4) * 8;

    const float* src = &W[(size_t)e * DDIM + k];
    floatx4 w0 = *(const floatx4*)src;
    floatx4 w1 = *(const floatx4*)(src + 4);

    half8 o;
#pragma unroll
    for (int q = 0; q < 4; ++q) {
        float f0 = w0[q], f1 = w1[q];
        _Float16 h0 = (_Float16)f0, h1 = (_Float16)f1;
        if (pl == 0) { o[q] = h0; o[4 + q] = h1; }
        else {
            o[q]     = (_Float16)((f0 - (float)h0) * 2048.0f);
            o[4 + q] = (_Float16)((f1 - (float)h1) * 2048.0f);
        }
    }
    *(half8*)(ws + (size_t)g * 8) = o;
}

// ---------------------------------------------------------------------------
// Fused router, register-pipelined, no LDS / barriers in the K-loop.
// Block = 32 tokens, 4 waves (t = token-half, h = K-half); grid 512
// (2 blocks/CU, 8 waves/CU). Fully unrolled 32-iter loop: x issued 2 iters
// ahead, B (coalesced, L1/L2-hot) 1 iter ahead, all into registers ->
// fine-grained vmcnt, loads stay in flight across iters. LDS only for the
// final h-reduce; wave-local softmax + stable top-2.
// ---------------------------------------------------------------------------
__global__ __launch_bounds__(256, 2) void router_kernel(
    const float* __restrict__ x,
    const _Float16* __restrict__ ws,
    const float* __restrict__ bias,
    float* __restrict__ out)
{
    __shared__ float rbuf[2048];   // 8 KB h-reduce scratch

    const int tid  = threadIdx.x;
    const int lane = tid & 63;
    const int wid  = tid >> 6;
    const int t    = wid >> 1;         // token half
    const int h    = wid & 1;          // K half (1024 each)
    const int t0   = blockIdx.x * 32 + t * 16;
    const int mrow = lane & 15;        // A token row / B expert col
    const int quad = lane >> 4;

    floatx4 acc_hh[4], acc_md[4];
#pragma unroll
    for (int j = 0; j < 4; ++j) { acc_hh[j] = (floatx4)0.0f; acc_md[j] = (floatx4)0.0f; }

    const float* xrow = x + (size_t)(t0 + mrow) * DDIM + h * 1024 + quad * 8;
    // wave's B stream: halves base + per-(i,j,pl) group of 512 halves
    const _Float16* wbase = ws + (size_t)h * 131072 + (size_t)lane * 8;

    floatx4 xs0[ITERS], xs1[ITERS];
    half8   bsh[ITERS][4], bsl[ITERS][4];

    // ---- prologue: x for iters 0,1; B for iter 0 ----
#pragma unroll
    for (int i = 0; i < 2; ++i) {
        xs0[i] = *(const floatx4*)(xrow + i * 32);
        xs1[i] = *(const floatx4*)(xrow + i * 32 + 4);
    }
#pragma unroll
    for (int j = 0; j < 4; ++j) {
        bsh[0][j] = *(const half8*)(wbase + (size_t)(j * 2    ) * 512);
        bsl[0][j] = *(const half8*)(wbase + (size_t)(j * 2 + 1) * 512);
    }

#pragma unroll
    for (int i = 0; i < ITERS; ++i) {
        // issue x(i+2) and B(i+1) first -- they stay in flight over compute(i)
        if (i + 2 < ITERS) {
            xs0[i + 2] = *(const floatx4*)(xrow + (i + 2) * 32);
            xs1[i + 2] = *(const floatx4*)(xrow + (i + 2) * 32 + 4);
        }
        if (i + 1 < ITERS) {
            const _Float16* gb = wbase + (size_t)(i + 1) * 4096;
#pragma unroll
            for (int j = 0; j < 4; ++j) {
                bsh[i + 1][j] = *(const half8*)(gb + (size_t)(j * 2    ) * 512);
                bsl[i + 1][j] = *(const half8*)(gb + (size_t)(j * 2 + 1) * 512);
            }
        }

        // convert x(i) to hi/lo fp16 fragments
        half8 a_hi, a_lo;
#pragma unroll
        for (int q = 0; q < 4; ++q) {
            float fv = xs0[i][q];
            _Float16 hh = (_Float16)fv;
            a_hi[q] = hh;
            a_lo[q] = (_Float16)((fv - (float)hh) * 2048.0f);
        }
#pragma unroll
        for (int q = 0; q < 4; ++q) {
            float fv = xs1[i][q];
            _Float16 hh = (_Float16)fv;
            a_hi[4 + q] = hh;
            a_lo[4 + q] = (_Float16)((fv - (float)hh) * 2048.0f);
        }

#pragma unroll
        for (int j = 0; j < 4; ++j) {
            acc_hh[j] = __builtin_amdgcn_mfma_f32_16x16x32_f16(a_hi, bsh[i][j], acc_hh[j], 0, 0, 0);
            acc_md[j] = __builtin_amdgcn_mfma_f32_16x16x32_f16(a_hi, bsl[i][j], acc_md[j], 0, 0, 0);
            acc_md[j] = __builtin_amdgcn_mfma_f32_16x16x32_f16(a_lo, bsh[i][j], acc_md[j], 0, 0, 0);
        }
    }

    // ---- combine planes; reduce h=1 -> h=0 through LDS ----
    float lg[4][4];
#pragma unroll
    for (int j = 0; j < 4; ++j)
#pragma unroll
        for (int r = 0; r < 4; ++r)
            lg[j][r] = acc_hh[j][r] + acc_md[j][r] * (1.0f / 2048.0f);

    __syncthreads();
    if (h == 1) {
#pragma unroll
        for (int j = 0; j < 4; ++j)
#pragma unroll
            for (int r = 0; r < 4; ++r)
                rbuf[t * 1024 + (j * 4 + r) * 64 + lane] = lg[j][r];
    }
    __syncthreads();
    if (h == 1) return;

#pragma unroll
    for (int j = 0; j < 4; ++j) {
        const float bj = bias[j * 16 + mrow];
#pragma unroll
        for (int r = 0; r < 4; ++r)
            lg[j][r] += rbuf[t * 1024 + (j * 4 + r) * 64 + lane] + bj;
    }

    // ---- epilogue: lane owns tokens t0 + quad*4 + r, experts j*16 + mrow ----
    const int c = mrow;
#pragma unroll
    for (int r = 0; r < 4; ++r) {
        const int trow = t0 + quad * 4 + r;

        float m = lg[0][r];
#pragma unroll
        for (int j = 1; j < 4; ++j) m = fmaxf(m, lg[j][r]);
#pragma unroll
        for (int off = 1; off <= 8; off <<= 1) m = fmaxf(m, __shfl_xor(m, off));

        float pj[4], s = 0.0f;
#pragma unroll
        for (int j = 0; j < 4; ++j) { pj[j] = __expf(lg[j][r] - m); s += pj[j]; }
#pragma unroll
        for (int off = 1; off <= 8; off <<= 1) s += __shfl_xor(s, off);
        const float rinv = 1.0f / s;

        // stable top-2 on logits (tie -> lower expert index)
        float v1 = -1e30f, v2 = -1e30f; int i1 = -1, i2 = -1;
#pragma unroll
        for (int j = 0; j < 4; ++j) {
            float v = lg[j][r]; int e = j * 16 + c;
            if (v > v1 || (v == v1 && e < i1)) { v2 = v1; i2 = i1; v1 = v; i1 = e; }
            else if (v > v2 || (v == v2 && e < i2)) { v2 = v; i2 = e; }
        }
#pragma unroll
        for (int off = 1; off <= 8; off <<= 1) {
            float u1 = __shfl_xor(v1, off); int q1 = __shfl_xor(i1, off);
            float u2 = __shfl_xor(v2, off); int q2 = __shfl_xor(i2, off);
            if (u1 > v1 || (u1 == v1 && q1 < i1)) {
                if (v1 > u2 || (v1 == u2 && i1 < q2)) { v2 = v1; i2 = i1; }
                else                                   { v2 = u2; i2 = q2; }
                v1 = u1; i1 = q1;
            } else {
                if (u1 > v2 || (u1 == v2 && q1 < i2)) { v2 = u1; i2 = q1; }
            }
        }

#pragma unroll
        for (int j = 0; j < 4; ++j) {
            const int col = j * 16 + c;
            const size_t o = (size_t)trow * NEXP + col;
            out[o]           = (col == i1 || col == i2) ? 1.0f : 0.0f;
            out[PSTRIDE + o] = pj[j] * rinv;
        }
    }
}

extern "C" void kernel_launch(void* const* d_in, const int* in_sizes, int n_in,
                              void* d_out, int out_size, void* d_ws, size_t ws_size,
                              hipStream_t stream) {
    const float* x = (const float*)d_in[0];   // [4,4096,2048] f32
    const float* W = (const float*)d_in[1];   // [64,2048] f32
    const float* b = (const float*)d_in[2];   // [64] f32
    (void)in_sizes; (void)n_in; (void)out_size; (void)ws_size;
    float* out = (float*)d_out;               // [masks | probs]

    _Float16* ws = (_Float16*)d_ws;           // 32768 x 16 B = 512 KB

    hipLaunchKernelGGL(wconv_kernel, dim3(128), dim3(256), 0, stream, W, ws);
    hipLaunchKernelGGL(router_kernel, dim3(NTOK / 32), dim3(256), 0, stream, x, ws, b, out);
}

// Round 10
// 209.638 us; speedup vs baseline: 1.1852x; 1.1852x over previous
//
#include <hip/hip_runtime.h>
#include <math.h>

// B=4, S=4096, D=2048, E=64, K=2
#define NTOK    16384
#define DDIM    2048
#define NEXP    64
#define PSTRIDE (NTOK * NEXP)

#define AS1 __attribute__((address_space(1)))
#define AS3 __attribute__((address_space(3)))

typedef _Float16 half8   __attribute__((ext_vector_type(8)));
typedef float    floatx4 __attribute__((ext_vector_type(4)));

// ---------------------------------------------------------------------------
// W (fp32 [64][2048]) -> d_ws: 32 slices (BK=64) x 16 KB, chunk order chosen
// to equal the LDS layout the GEMM stages into (pure linear DMA):
//   slice s, 16B chunk c = ((kk*2+pl)*64 + e)*4 + q  holds plane pl
//   (0: hi, 1: lo*2^11) of W[e][s*64 + kk*32 + q*8 .. +8).
// ---------------------------------------------------------------------------
__global__ __launch_bounds__(256) void wconv_kernel(
    const float* __restrict__ W, _Float16* __restrict__ ws)
{
    const int g  = blockIdx.x * 256 + threadIdx.x;   // 32768 chunks
    const int s  = g >> 10;
    const int c  = g & 1023;
    const int q  = c & 3;
    const int e  = (c >> 2) & 63;
    const int pl = (c >> 8) & 1;
    const int kk = (c >> 9) & 1;
    const int k  = s * 64 + kk * 32 + q * 8;

    const float* src = &W[(size_t)e * DDIM + k];
    floatx4 w0 = *(const floatx4*)src;
    floatx4 w1 = *(const floatx4*)(src + 4);

    half8 o;
#pragma unroll
    for (int i = 0; i < 4; ++i) {
        float f0 = w0[i], f1 = w1[i];
        _Float16 h0 = (_Float16)f0, h1 = (_Float16)f1;
        if (pl == 0) { o[i] = h0; o[4 + i] = h1; }
        else {
            o[i]     = (_Float16)((f0 - (float)h0) * 2048.0f);
            o[4 + i] = (_Float16)((f1 - (float)h1) * 2048.0f);
        }
    }
    *(half8*)(ws + (size_t)g * 8) = o;
}

// ---------------------------------------------------------------------------
// Partial GEMM. Grid 256 = 64 M-tiles (256 tokens) x 4 K-splits; 512 threads
// (8 waves) per block -> 1 block/CU, 8 waves/CU. Wave owns 32 tokens (2
// sub-tiles of 16). 8 phases of BK=64: B slice (16 KB) DMA'd into dbuf LDS,
// x prefetched one phase ahead into regs. B fetched once per block -> B
// traffic 32 MB total (vs 256 MB in R7). Partials (hi+lo combined) to d_ws.
// ---------------------------------------------------------------------------
__global__ __launch_bounds__(512, 2) void gemm_partial(
    const float* __restrict__ x,
    const _Float16* __restrict__ ws,
    float* __restrict__ part)
{
    __shared__ __align__(16) char lds[2][16384];

    const int tid  = threadIdx.x;
    const int lane = tid & 63;
    const int wid  = tid >> 6;          // 0..7
    const int bm   = blockIdx.x >> 2;   // 0..63  M-tile
    const int ks   = blockIdx.x & 3;    // K-split
    const int T0   = bm * 256;
    const int mrow = lane & 15;
    const int quad = lane >> 4;

    floatx4 acc_hh[2][4], acc_md[2][4];
#pragma unroll
    for (int m = 0; m < 2; ++m)
#pragma unroll
        for (int j = 0; j < 4; ++j) { acc_hh[m][j] = (floatx4)0.0f; acc_md[m][j] = (floatx4)0.0f; }

    // x base: row (T0 + wid*32 + mrow), k base ks*512 + quad*8
    const float* xbase = x + (size_t)(T0 + wid * 32 + mrow) * DDIM + ks * 512 + quad * 8;
    // B slice stream (slices ks*8 .. ks*8+7), per-lane 16B source
    const char* wsrc = (const char*)ws + (size_t)(ks * 8) * 16384 + (size_t)lane * 16;

#define DMA(P, B)                                                              \
    {                                                                          \
        const char* gs = wsrc + (size_t)(P) * 16384;                           \
        __builtin_amdgcn_global_load_lds(                                      \
            (const AS1 unsigned int*)(const void*)(gs + wid * 1024),           \
            (AS3 unsigned int*)(void*)&lds[B][wid * 1024], 16, 0, 0);          \
        __builtin_amdgcn_global_load_lds(                                      \
            (const AS1 unsigned int*)(const void*)(gs + 8192 + wid * 1024),    \
            (AS3 unsigned int*)(void*)&lds[B][8192 + wid * 1024], 16, 0, 0);   \
    }

#define XLOAD(P, DST)                                                          \
    {                                                                          \
        _Pragma("unroll")                                                      \
        for (int m_ = 0; m_ < 2; ++m_)                                         \
        _Pragma("unroll")                                                      \
        for (int kk_ = 0; kk_ < 2; ++kk_)                                      \
        _Pragma("unroll")                                                      \
        for (int hf_ = 0; hf_ < 2; ++hf_)                                      \
            (DST)[m_ * 4 + kk_ * 2 + hf_] = *(const floatx4*)(                 \
                xbase + (size_t)m_ * 16 * DDIM + (P) * 64 + kk_ * 32 + hf_ * 4); \
    }

    floatx4 xc[8], xn[8];

    // ---- prologue ----
    XLOAD(0, xc);
    DMA(0, 0);
    __syncthreads();

    for (int p = 0; p < 8; ++p) {
        if (p < 7) {
            XLOAD(p + 1, xn);
            DMA(p + 1, (p + 1) & 1);
        }

        const _Float16* lb = (const _Float16*)lds[p & 1];
#pragma unroll
        for (int kk = 0; kk < 2; ++kk) {
            half8 bh[4], bl[4];
#pragma unroll
            for (int j = 0; j < 4; ++j) {
                const int e = j * 16 + mrow;
                bh[j] = *(const half8*)(lb + ((kk * 2 + 0) * 64 + e) * 32 + quad * 8);
                bl[j] = *(const half8*)(lb + ((kk * 2 + 1) * 64 + e) * 32 + quad * 8);
            }
#pragma unroll
            for (int m = 0; m < 2; ++m) {
                half8 a_hi, a_lo;
                floatx4 v0 = xc[m * 4 + kk * 2];
                floatx4 v1 = xc[m * 4 + kk * 2 + 1];
#pragma unroll
                for (int q = 0; q < 4; ++q) {
                    float fv = v0[q];
                    _Float16 hh = (_Float16)fv;
                    a_hi[q] = hh;
                    a_lo[q] = (_Float16)((fv - (float)hh) * 2048.0f);
                }
#pragma unroll
                for (int q = 0; q < 4; ++q) {
                    float fv = v1[q];
                    _Float16 hh = (_Float16)fv;
                    a_hi[4 + q] = hh;
                    a_lo[4 + q] = (_Float16)((fv - (float)hh) * 2048.0f);
                }
#pragma unroll
                for (int j = 0; j < 4; ++j) {
                    acc_hh[m][j] = __builtin_amdgcn_mfma_f32_16x16x32_f16(a_hi, bh[j], acc_hh[m][j], 0, 0, 0);
                    acc_md[m][j] = __builtin_amdgcn_mfma_f32_16x16x32_f16(a_hi, bl[j], acc_md[m][j], 0, 0, 0);
                    acc_md[m][j] = __builtin_amdgcn_mfma_f32_16x16x32_f16(a_lo, bh[j], acc_md[m][j], 0, 0, 0);
                }
            }
        }

        if (p < 7) {
#pragma unroll
            for (int i = 0; i < 8; ++i) xc[i] = xn[i];
        }
        __syncthreads();
    }

    // ---- write partials (planes combined), coalesced 256B stores ----
    // layout: part[(ks*64+bm)*16384 + wid*2048 + m*1024 + (j*4+r)*64 + lane]
    float* pw = part + ((size_t)(ks * 64 + bm)) * 16384 + wid * 2048 + lane;
#pragma unroll
    for (int m = 0; m < 2; ++m)
#pragma unroll
        for (int j = 0; j < 4; ++j)
#pragma unroll
            for (int r = 0; r < 4; ++r)
                pw[m * 1024 + (j * 4 + r) * 64] =
                    acc_hh[m][j][r] + acc_md[m][j][r] * (1.0f / 2048.0f);
}

// ---------------------------------------------------------------------------
// Reduce 4 K-split partials per token, then softmax + stable top-2.
// Wave u owns 16 tokens: bm = u>>4, w8 = (u>>1)&7, m = u&1.
// ---------------------------------------------------------------------------
__global__ __launch_bounds__(256) void reduce_epilogue(
    const float* __restrict__ part,
    const float* __restrict__ bias,
    float* __restrict__ out)
{
    const int tid  = threadIdx.x;
    const int lane = tid & 63;
    const int u    = blockIdx.x * 4 + (tid >> 6);   // 0..1023
    const int bm   = u >> 4;
    const int w8   = (u >> 1) & 7;
    const int m    = u & 1;
    const int mrow = lane & 15;
    const int quad = lane >> 4;
    const int tb   = bm * 256 + w8 * 32 + m * 16;   // wave's token base

    const float* pb = part + (size_t)bm * 16384 + w8 * 2048 + m * 1024 + lane;

    float lg[4][4];
#pragma unroll
    for (int j = 0; j < 4; ++j) {
        const float bj = bias[j * 16 + mrow];
#pragma unroll
        for (int r = 0; r < 4; ++r) {
            const int f = j * 4 + r;
            float s0 = pb[(size_t)0 * 1048576 + f * 64];
            float s1 = pb[(size_t)1 * 1048576 + f * 64];
            float s2 = pb[(size_t)2 * 1048576 + f * 64];
            float s3 = pb[(size_t)3 * 1048576 + f * 64];
            lg[j][r] = (s0 + s1) + (s2 + s3) + bj;
        }
    }

    const int c = mrow;
#pragma unroll
    for (int r = 0; r < 4; ++r) {
        const int trow = tb + quad * 4 + r;

        float mx = lg[0][r];
#pragma unroll
        for (int j = 1; j < 4; ++j) mx = fmaxf(mx, lg[j][r]);
#pragma unroll
        for (int off = 1; off <= 8; off <<= 1) mx = fmaxf(mx, __shfl_xor(mx, off));

        float pj[4], s = 0.0f;
#pragma unroll
        for (int j = 0; j < 4; ++j) { pj[j] = __expf(lg[j][r] - mx); s += pj[j]; }
#pragma unroll
        for (int off = 1; off <= 8; off <<= 1) s += __shfl_xor(s, off);
        const float rinv = 1.0f / s;

        // stable top-2 on logits (tie -> lower expert index)
        float v1 = -1e30f, v2 = -1e30f; int i1 = -1, i2 = -1;
#pragma unroll
        for (int j = 0; j < 4; ++j) {
            float v = lg[j][r]; int e = j * 16 + c;
            if (v > v1 || (v == v1 && e < i1)) { v2 = v1; i2 = i1; v1 = v; i1 = e; }
            else if (v > v2 || (v == v2 && e < i2)) { v2 = v; i2 = e; }
        }
#pragma unroll
        for (int off = 1; off <= 8; off <<= 1) {
            float u1 = __shfl_xor(v1, off); int q1 = __shfl_xor(i1, off);
            float u2 = __shfl_xor(v2, off); int q2 = __shfl_xor(i2, off);
            if (u1 > v1 || (u1 == v1 && q1 < i1)) {
                if (v1 > u2 || (v1 == u2 && i1 < q2)) { v2 = v1; i2 = i1; }
                else                                   { v2 = u2; i2 = q2; }
                v1 = u1; i1 = q1;
            } else {
                if (u1 > v2 || (u1 == v2 && q1 < i2)) { v2 = u1; i2 = q1; }
            }
        }

#pragma unroll
        for (int j = 0; j < 4; ++j) {
            const int col = j * 16 + c;
            const size_t o = (size_t)trow * NEXP + col;
            out[o]           = (col == i1 || col == i2) ? 1.0f : 0.0f;
            out[PSTRIDE + o] = pj[j] * rinv;
        }
    }
}

extern "C" void kernel_launch(void* const* d_in, const int* in_sizes, int n_in,
                              void* d_out, int out_size, void* d_ws, size_t ws_size,
                              hipStream_t stream) {
    const float* x = (const float*)d_in[0];   // [4,4096,2048] f32
    const float* W = (const float*)d_in[1];   // [64,2048] f32
    const float* b = (const float*)d_in[2];   // [64] f32
    (void)in_sizes; (void)n_in; (void)out_size; (void)ws_size;
    float* out = (float*)d_out;               // [masks | probs]

    _Float16* ws  = (_Float16*)d_ws;                       // 512 KB W hi/lo
    float*    prt = (float*)((char*)d_ws + (1 << 19));     // 16 MB partials

    hipLaunchKernelGGL(wconv_kernel,    dim3(128), dim3(256), 0, stream, W, ws);
    hipLaunchKernelGGL(gemm_partial,    dim3(256), dim3(512), 0, stream, x, ws, prt);
    hipLaunchKernelGGL(reduce_epilogue, dim3(256), dim3(256), 0, stream, prt, b, out);
}

// Round 11
// 204.585 us; speedup vs baseline: 1.2145x; 1.0247x over previous
//
#include <hip/hip_runtime.h>
#include <math.h>

// B=4, S=4096, D=2048, E=64, K=2
#define NTOK    16384
#define DDIM    2048
#define NEXP    64
#define PSTRIDE (NTOK * NEXP)
#define NPH     16                  // phases; each stages 128 k (32 k per h-quarter)
#define SLICE_B 32768               // bytes per phase slice

#define AS1 __attribute__((address_space(1)))
#define AS3 __attribute__((address_space(3)))

typedef _Float16 half8   __attribute__((ext_vector_type(8)));
typedef float    floatx4 __attribute__((ext_vector_type(4)));

// ---------------------------------------------------------------------------
// W (fp32 [64][2048]) -> d_ws: 16 slices x 32 KB. Slice p, 16B chunk
// L = ((h*2+pl)*64 + e)*4 + q'  holds plane pl (0 hi, 1 lo*2^11) of
// W[e][k = h*512 + p*32 + q*8 .. +8), q = q' ^ ((e ^ (e>>2)) & 3).
// This is byte-for-byte the LDS layout the router DMAs into (linear copy);
// the XOR swizzle keeps B-frag ds_read_b128 at <=2-way banking.
// ---------------------------------------------------------------------------
__global__ __launch_bounds__(256) void wconv_kernel(
    const float* __restrict__ W, _Float16* __restrict__ ws)
{
    const int g  = blockIdx.x * 256 + threadIdx.x;   // 0..32767 chunks
    const int p  = g >> 11;
    const int L  = g & 2047;
    const int qp = L & 3;
    const int e  = (L >> 2) & 63;
    const int pl = (L >> 8) & 1;
    const int h  = (L >> 9) & 3;
    const int q  = qp ^ ((e ^ (e >> 2)) & 3);
    const int k  = h * 512 + p * 32 + q * 8;

    const float* src = &W[(size_t)e * DDIM + k];
    floatx4 w0 = *(const floatx4*)src;
    floatx4 w1 = *(const floatx4*)(src + 4);

    half8 o;
#pragma unroll
    for (int i = 0; i < 4; ++i) {
        float f0 = w0[i], f1 = w1[i];
        _Float16 h0 = (_Float16)f0, h1 = (_Float16)f1;
        if (pl == 0) { o[i] = h0; o[4 + i] = h1; }
        else {
            o[i]     = (_Float16)((f0 - (float)h0) * 2048.0f);
            o[4 + i] = (_Float16)((f1 - (float)h1) * 2048.0f);
        }
    }
    *(half8*)(ws + (size_t)g * 8) = o;
}

// ---------------------------------------------------------------------------
// Fused router at 16 waves/CU. Block = 32 tokens, 512 thr = 8 waves
// (t = token-half, h = K-quarter of 512). Grid 512 = 2 blocks/CU,
// 4 waves/SIMD. 16 phases: DMA next 32 KB W slice into dbuf LDS + prefetch
// next x, compute 1 k-step (12 MFMA) from current buffer, 1 barrier/phase.
// In-block 4-way h-reduce; wave-local softmax + stable top-2.
// ---------------------------------------------------------------------------
__global__ __launch_bounds__(512, 4) void router_kernel(
    const float* __restrict__ x,
    const _Float16* __restrict__ ws,
    const float* __restrict__ bias,
    float* __restrict__ out)
{
    __shared__ __align__(16) char lds[2][SLICE_B];   // 64 KB -> 2 blocks/CU

    const int tid  = threadIdx.x;
    const int lane = tid & 63;
    const int wid  = tid >> 6;          // 0..7
    const int t    = wid >> 2;          // token half
    const int h    = wid & 3;           // K quarter (512 each)
    const int t0   = blockIdx.x * 32 + t * 16;
    const int mrow = lane & 15;         // A token row / B expert col
    const int quad = lane >> 4;

    floatx4 acc_hh[4], acc_md[4];
#pragma unroll
    for (int j = 0; j < 4; ++j) { acc_hh[j] = (floatx4)0.0f; acc_md[j] = (floatx4)0.0f; }

    // x: row (t0 + t*16 + mrow), phase-p k = h*512 + p*32 + quad*8
    const float* xrow = x + (size_t)(t0 + mrow) * DDIM + h * 512 + quad * 8;

    // B-fragment LDS offsets (halves) per j: hi at boff[j], lo at boff[j]+2048
    int boff[4];
#pragma unroll
    for (int j = 0; j < 4; ++j) {
        const int e = j * 16 + mrow;
        const int s = (e ^ (e >> 2)) & 3;
        boff[j] = (((h * 2) * 64 + e) * 4 + (quad ^ s)) * 8;
    }

#define DMA(P, B)                                                              \
    {                                                                          \
        const char* gs = (const char*)ws + (size_t)(P) * SLICE_B + (size_t)tid * 16; \
        char*       ld = &lds[B][0] + tid * 16;                                \
        _Pragma("unroll")                                                      \
        for (int i_ = 0; i_ < 4; ++i_)                                         \
            __builtin_amdgcn_global_load_lds(                                  \
                (const AS1 unsigned int*)(const void*)(gs + i_ * 8192),        \
                (AS3 unsigned int*)(void*)(ld + i_ * 8192), 16, 0, 0);         \
    }

    // ---- prologue ----
    DMA(0, 0);
    floatx4 xc0 = *(const floatx4*)(xrow);
    floatx4 xc1 = *(const floatx4*)(xrow + 4);
    __syncthreads();

#pragma unroll 2
    for (int p = 0; p < NPH; ++p) {
        floatx4 xn0, xn1;
        if (p < NPH - 1) {
            DMA(p + 1, (p + 1) & 1);
            xn0 = *(const floatx4*)(xrow + (p + 1) * 32);
            xn1 = *(const floatx4*)(xrow + (p + 1) * 32 + 4);
        }

        // convert x(p) to hi/lo fp16 fragments
        half8 a_hi, a_lo;
#pragma unroll
        for (int q = 0; q < 4; ++q) {
            float fv = xc0[q];
            _Float16 hh = (_Float16)fv;
            a_hi[q] = hh;
            a_lo[q] = (_Float16)((fv - (float)hh) * 2048.0f);
        }
#pragma unroll
        for (int q = 0; q < 4; ++q) {
            float fv = xc1[q];
            _Float16 hh = (_Float16)fv;
            a_hi[4 + q] = hh;
            a_lo[4 + q] = (_Float16)((fv - (float)hh) * 2048.0f);
        }

        const _Float16* lb = (const _Float16*)lds[p & 1];
#pragma unroll
        for (int j = 0; j < 4; ++j) {
            half8 bh = *(const half8*)(lb + boff[j]);
            half8 bl = *(const half8*)(lb + boff[j] + 2048);
            acc_hh[j] = __builtin_amdgcn_mfma_f32_16x16x32_f16(a_hi, bh, acc_hh[j], 0, 0, 0);
            acc_md[j] = __builtin_amdgcn_mfma_f32_16x16x32_f16(a_hi, bl, acc_md[j], 0, 0, 0);
            acc_md[j] = __builtin_amdgcn_mfma_f32_16x16x32_f16(a_lo, bh, acc_md[j], 0, 0, 0);
        }

        if (p < NPH - 1) { xc0 = xn0; xc1 = xn1; }
        __syncthreads();
    }

    // ---- combine planes; reduce h=1..3 -> h=0 through LDS ----
    float lg[4][4];
#pragma unroll
    for (int j = 0; j < 4; ++j)
#pragma unroll
        for (int r = 0; r < 4; ++r)
            lg[j][r] = acc_hh[j][r] + acc_md[j][r] * (1.0f / 2048.0f);

    float* rbuf = (float*)&lds[0][0];   // 24 KB: [(h-1)*2+t][frag][lane]
    if (h > 0) {
#pragma unroll
        for (int j = 0; j < 4; ++j)
#pragma unroll
            for (int r = 0; r < 4; ++r)
                rbuf[((h - 1) * 2 + t) * 1024 + (j * 4 + r) * 64 + lane] = lg[j][r];
    }
    __syncthreads();
    if (h > 0) return;

#pragma unroll
    for (int j = 0; j < 4; ++j) {
        const float bj = bias[j * 16 + mrow];
#pragma unroll
        for (int r = 0; r < 4; ++r) {
            const int f = (j * 4 + r) * 64 + lane;
            lg[j][r] += rbuf[t * 1024 + f] + rbuf[(2 + t) * 1024 + f]
                      + rbuf[(4 + t) * 1024 + f] + bj;
        }
    }

    // ---- epilogue: lane owns tokens t0 + quad*4 + r, experts j*16 + mrow ----
    const int c = mrow;
#pragma unroll
    for (int r = 0; r < 4; ++r) {
        const int trow = t0 + quad * 4 + r;

        float m = lg[0][r];
#pragma unroll
        for (int j = 1; j < 4; ++j) m = fmaxf(m, lg[j][r]);
#pragma unroll
        for (int off = 1; off <= 8; off <<= 1) m = fmaxf(m, __shfl_xor(m, off));

        float pj[4], s = 0.0f;
#pragma unroll
        for (int j = 0; j < 4; ++j) { pj[j] = __expf(lg[j][r] - m); s += pj[j]; }
#pragma unroll
        for (int off = 1; off <= 8; off <<= 1) s += __shfl_xor(s, off);
        const float rinv = 1.0f / s;

        // stable top-2 on logits (tie -> lower expert index)
        float v1 = -1e30f, v2 = -1e30f; int i1 = -1, i2 = -1;
#pragma unroll
        for (int j = 0; j < 4; ++j) {
            float v = lg[j][r]; int e = j * 16 + c;
            if (v > v1 || (v == v1 && e < i1)) { v2 = v1; i2 = i1; v1 = v; i1 = e; }
            else if (v > v2 || (v == v2 && e < i2)) { v2 = v; i2 = e; }
        }
#pragma unroll
        for (int off = 1; off <= 8; off <<= 1) {
            float u1 = __shfl_xor(v1, off); int q1 = __shfl_xor(i1, off);
            float u2 = __shfl_xor(v2, off); int q2 = __shfl_xor(i2, off);
            if (u1 > v1 || (u1 == v1 && q1 < i1)) {
                if (v1 > u2 || (v1 == u2 && i1 < q2)) { v2 = v1; i2 = i1; }
                else                                   { v2 = u2; i2 = q2; }
                v1 = u1; i1 = q1;
            } else {
                if (u1 > v2 || (u1 == v2 && q1 < i2)) { v2 = u1; i2 = q1; }
            }
        }

#pragma unroll
        for (int j = 0; j < 4; ++j) {
            const int col = j * 16 + c;
            const size_t o = (size_t)trow * NEXP + col;
            out[o]           = (col == i1 || col == i2) ? 1.0f : 0.0f;
            out[PSTRIDE + o] = pj[j] * rinv;
        }
    }
}

extern "C" void kernel_launch(void* const* d_in, const int* in_sizes, int n_in,
                              void* d_out, int out_size, void* d_ws, size_t ws_size,
                              hipStream_t stream) {
    const float* x = (const float*)d_in[0];   // [4,4096,2048] f32
    const float* W = (const float*)d_in[1];   // [64,2048] f32
    const float* b = (const float*)d_in[2];   // [64] f32
    (void)in_sizes; (void)n_in; (void)out_size; (void)ws_size;
    float* out = (float*)d_out;               // [masks | probs]

    _Float16* ws = (_Float16*)d_ws;           // 16 slices x 32 KB = 512 KB

    hipLaunchKernelGGL(wconv_kernel,  dim3(128), dim3(256), 0, stream, W, ws);
    hipLaunchKernelGGL(router_kernel, dim3(NTOK / 32), dim3(512), 0, stream, x, ws, b, out);
}